// Round 1
// baseline (153.854 us; speedup 1.0000x reference)
//
#include <hip/hip_runtime.h>

// TSM temporal shift: x (B_T=128, C=256, H=56, W=56) fp32, num_segments=8, fold_div=3.
// B=16, T=8, fold=85. Flat layout: i = ((b*T + t)*C + c)*HW + hw.
// out[c <  fold]      = (t < T-1) ? in[i + CHW] : 0
// out[fold<=c<2fold]  = (t > 0)   ? in[i - CHW] : 0
// out[c >= 2fold]     = in[i]
// Vectorized float4: HW=3136 divisible by 4, (c,t) constant within a float4.

namespace {
constexpr int kT      = 8;
constexpr int kC      = 256;
constexpr int kHW     = 56 * 56;          // 3136
constexpr int kHW4    = kHW / 4;          // 784
constexpr int kCHW4   = kC * kHW4;        // 200704 (float4 units)
constexpr int kFold   = kC / 3;           // 85
constexpr int kN4     = 128 * kC * kHW4;  // 25,690,112 float4 elements
}

__global__ __launch_bounds__(256) void tsm_shift_kernel(
    const float4* __restrict__ in, float4* __restrict__ out) {
  const int stride = gridDim.x * blockDim.x;
  for (int i = blockIdx.x * blockDim.x + threadIdx.x; i < kN4; i += stride) {
    const int plane = i / kHW4;            // bt*C + c   (magic-mul div)
    const int c = plane & (kC - 1);        // C=256 pow2
    const int t = (plane >> 8) & (kT - 1); // T=8 pow2
    float4 v;
    if (c < kFold) {
      v = (t < kT - 1) ? in[i + kCHW4] : make_float4(0.f, 0.f, 0.f, 0.f);
    } else if (c < 2 * kFold) {
      v = (t > 0) ? in[i - kCHW4] : make_float4(0.f, 0.f, 0.f, 0.f);
    } else {
      v = in[i];
    }
    out[i] = v;
  }
}

extern "C" void kernel_launch(void* const* d_in, const int* in_sizes, int n_in,
                              void* d_out, int out_size, void* d_ws, size_t ws_size,
                              hipStream_t stream) {
  const float4* x = (const float4*)d_in[0];
  float4* out = (float4*)d_out;
  // Memory-bound: ~2048 blocks of 256, grid-stride the rest.
  const int block = 256;
  int grid = (kN4 + block - 1) / block;
  if (grid > 2048) grid = 2048;
  tsm_shift_kernel<<<grid, block, 0, stream>>>(x, out);
}

// Round 3
// 149.035 us; speedup vs baseline: 1.0323x; 1.0323x over previous
//
#include <hip/hip_runtime.h>

// TSM temporal shift: x (B_T=128, C=256, H=56, W=56) fp32, num_segments=8, fold_div=3.
// B=16, T=8, fold=85. Flat layout: i = ((b*T + t)*C + c)*HW + hw.
// out[c <  fold]      = (t < T-1) ? in[i + CHW] : 0
// out[fold<=c<2fold]  = (t > 0)   ? in[i - CHW] : 0
// out[c >= 2fold]     = in[i]
// float4-vectorized (HW=3136 % 4 == 0; (c,t) constant within a float4).
// R1: 4x block-stride unroll + nontemporal load/store (streaming, zero reuse).
// R2 fix: nontemporal builtins need native clang vectors, not HIP_vector_type.

namespace {
typedef float f32x4 __attribute__((ext_vector_type(4)));

constexpr int kT    = 8;
constexpr int kC    = 256;
constexpr int kHW4  = (56 * 56) / 4;       // 784
constexpr int kCHW4 = kC * kHW4;           // 200704 (f32x4 units)
constexpr int kFold = kC / 3;              // 85
constexpr int kN4   = 128 * kC * kHW4;     // 25,690,112 f32x4 elements
constexpr int kBlk  = 256;
constexpr int kUnroll = 4;
constexpr int kChunk  = kBlk * kUnroll;    // 1024; kN4 % 1024 == 0 -> no tail
constexpr int kNChunks = kN4 / kChunk;     // 25088
}

__global__ __launch_bounds__(kBlk) void tsm_shift_kernel(
    const f32x4* __restrict__ in, f32x4* __restrict__ out) {
  const f32x4 zero = {0.f, 0.f, 0.f, 0.f};
  for (int chunk = blockIdx.x; chunk < kNChunks; chunk += gridDim.x) {
    const int base = chunk * kChunk + threadIdx.x;
    f32x4 v[kUnroll];
#pragma unroll
    for (int j = 0; j < kUnroll; ++j) {
      const int i = base + j * kBlk;
      const int plane = i / kHW4;            // magic-mul div
      const int c = plane & (kC - 1);        // C=256 pow2
      const int t = (plane >> 8) & (kT - 1); // T=8 pow2
      if (c < kFold) {
        v[j] = (t < kT - 1) ? __builtin_nontemporal_load(&in[i + kCHW4]) : zero;
      } else if (c < 2 * kFold) {
        v[j] = (t > 0) ? __builtin_nontemporal_load(&in[i - kCHW4]) : zero;
      } else {
        v[j] = __builtin_nontemporal_load(&in[i]);
      }
    }
#pragma unroll
    for (int j = 0; j < kUnroll; ++j) {
      __builtin_nontemporal_store(v[j], &out[base + j * kBlk]);
    }
  }
}

extern "C" void kernel_launch(void* const* d_in, const int* in_sizes, int n_in,
                              void* d_out, int out_size, void* d_ws, size_t ws_size,
                              hipStream_t stream) {
  const f32x4* x = (const f32x4*)d_in[0];
  f32x4* out = (f32x4*)d_out;
  tsm_shift_kernel<<<2048, kBlk, 0, stream>>>(x, out);
}

// Round 4
// 141.011 us; speedup vs baseline: 1.0911x; 1.0569x over previous
//
#include <hip/hip_runtime.h>

// TSM temporal shift: x (B_T=128, C=256, H=56, W=56) fp32, num_segments=8, fold_div=3.
// B=16, T=8, fold=85. Flat index i = ((b*T + t)*C + c)*HW + hw.
// out[c <  fold]      = (t < T-1) ? in[i + CHW] : 0
// out[fold<=c<2fold]  = (t > 0)   ? in[i - CHW] : 0
// out[c >= 2fold]     = in[i]
// f32x4-vectorized (HW=3136 % 4 == 0; (c,t) constant within an f32x4).
// R1: unroll + nontemporal (streaming, zero reuse). R3: +3% only.
// R4: perfect balance (1792 blocks x exactly 7 chunks), unroll 8 (deeper MLP),
//     branchless (off,valid) select -> single predicated load path.

namespace {
typedef float f32x4 __attribute__((ext_vector_type(4)));

constexpr int kT    = 8;
constexpr int kC    = 256;
constexpr int kHW4  = (56 * 56) / 4;       // 784
constexpr int kCHW4 = kC * kHW4;           // 200704 (f32x4 units)
constexpr int kFold = kC / 3;              // 85
constexpr int kN4   = 128 * kC * kHW4;     // 25,690,112 f32x4 elements
constexpr int kBlk  = 256;
constexpr int kUnroll = 8;
constexpr int kChunk  = kBlk * kUnroll;    // 2048; kN4 % 2048 == 0
constexpr int kNChunks = kN4 / kChunk;     // 12544 = 1792 * 7 exactly
constexpr int kGrid = 1792;                // 7 blocks/CU, perfectly balanced
}

__global__ __launch_bounds__(kBlk) void tsm_shift_kernel(
    const f32x4* __restrict__ in, f32x4* __restrict__ out) {
  const f32x4 zero = {0.f, 0.f, 0.f, 0.f};
  for (int chunk = blockIdx.x; chunk < kNChunks; chunk += kGrid) {
    const int base = chunk * kChunk + threadIdx.x;
    f32x4 v[kUnroll];
#pragma unroll
    for (int j = 0; j < kUnroll; ++j) {
      const int i = base + j * kBlk;
      const int plane = i / kHW4;            // magic-mul div
      const int c = plane & (kC - 1);        // C=256 pow2
      const int t = (plane >> 8) & (kT - 1); // T=8 pow2
      // Branchless: one load path, predicated by `valid`.
      int off;
      bool valid;
      if (c < kFold)          { off =  kCHW4; valid = (t < kT - 1); }
      else if (c < 2 * kFold) { off = -kCHW4; valid = (t > 0); }
      else                    { off = 0;      valid = true; }
      v[j] = valid ? __builtin_nontemporal_load(&in[i + off]) : zero;
    }
#pragma unroll
    for (int j = 0; j < kUnroll; ++j) {
      __builtin_nontemporal_store(v[j], &out[base + j * kBlk]);
    }
  }
}

extern "C" void kernel_launch(void* const* d_in, const int* in_sizes, int n_in,
                              void* d_out, int out_size, void* d_ws, size_t ws_size,
                              hipStream_t stream) {
  const f32x4* x = (const f32x4*)d_in[0];
  f32x4* out = (f32x4*)d_out;
  tsm_shift_kernel<<<kGrid, kBlk, 0, stream>>>(x, out);
}

// Round 5
// 138.960 us; speedup vs baseline: 1.1072x; 1.0148x over previous
//
#include <hip/hip_runtime.h>

// TSM temporal shift: x (B_T=128, C=256, H=56, W=56) fp32, num_segments=8, fold_div=3.
// B=16, T=8, fold=85. Flat index i = ((b*T + t)*C + c)*HW + hw.
// out[c <  fold]      = (t < T-1) ? in[i + CHW] : 0
// out[fold<=c<2fold]  = (t > 0)   ? in[i - CHW] : 0
// out[c >= 2fold]     = in[i]
// f32x4-vectorized (HW=3136 % 4 == 0; (c,t) constant within an f32x4).
// R4: 1792 blocks x 7 chunks (perfect balance), unroll 8, branchless, nt. 141 us.
// R5: 2-deep software pipeline with double-buffered registers — issue chunk k+1's
//     loads BEFORE chunk k's stores so register reuse doesn't serialize on the
//     stores' vmcnt retirement. Static (k&1) parity under full unroll -> regs.

namespace {
typedef float f32x4 __attribute__((ext_vector_type(4)));

constexpr int kT    = 8;
constexpr int kC    = 256;
constexpr int kHW4  = (56 * 56) / 4;       // 784
constexpr int kCHW4 = kC * kHW4;           // 200704 (f32x4 units)
constexpr int kFold = kC / 3;              // 85
constexpr int kN4   = 128 * kC * kHW4;     // 25,690,112 f32x4 elements
constexpr int kBlk  = 256;
constexpr int kUnroll = 8;
constexpr int kChunk  = kBlk * kUnroll;    // 2048; kN4 % 2048 == 0
constexpr int kNChunks = kN4 / kChunk;     // 12544 = 1792 * 7 exactly
constexpr int kGrid  = 1792;               // 7 blocks/CU, perfectly balanced
constexpr int kSteps = kNChunks / kGrid;   // 7 chunks per block
constexpr int kStride = kGrid * kChunk;    // 3,670,016 f32x4 between chunks
}

__device__ __forceinline__ void load_chunk(f32x4* v, int base,
                                           const f32x4* __restrict__ in) {
  const f32x4 zero = {0.f, 0.f, 0.f, 0.f};
#pragma unroll
  for (int j = 0; j < kUnroll; ++j) {
    const int i = base + j * kBlk;
    const int plane = i / kHW4;            // magic-mul div
    const int c = plane & (kC - 1);        // C=256 pow2
    const int t = (plane >> 8) & (kT - 1); // T=8 pow2
    int off;
    bool valid;
    if (c < kFold)          { off =  kCHW4; valid = (t < kT - 1); }
    else if (c < 2 * kFold) { off = -kCHW4; valid = (t > 0); }
    else                    { off = 0;      valid = true; }
    v[j] = valid ? __builtin_nontemporal_load(&in[i + off]) : zero;
  }
}

__device__ __forceinline__ void store_chunk(const f32x4* v, int base,
                                            f32x4* __restrict__ out) {
#pragma unroll
  for (int j = 0; j < kUnroll; ++j)
    __builtin_nontemporal_store(v[j], &out[base + j * kBlk]);
}

__global__ __launch_bounds__(kBlk) void tsm_shift_kernel(
    const f32x4* __restrict__ in, f32x4* __restrict__ out) {
  f32x4 A[kUnroll], B[kUnroll];
  int base = blockIdx.x * kChunk + (int)threadIdx.x;
  load_chunk(A, base, in);
#pragma unroll
  for (int k = 0; k < kSteps; ++k) {
    f32x4* cur = (k & 1) ? B : A;   // static after unroll -> stays in registers
    f32x4* nxt = (k & 1) ? A : B;
    if (k + 1 < kSteps) load_chunk(nxt, base + kStride, in);
    store_chunk(cur, base, out);
    base += kStride;
  }
}

extern "C" void kernel_launch(void* const* d_in, const int* in_sizes, int n_in,
                              void* d_out, int out_size, void* d_ws, size_t ws_size,
                              hipStream_t stream) {
  const f32x4* x = (const f32x4*)d_in[0];
  f32x4* out = (f32x4*)d_out;
  tsm_shift_kernel<<<kGrid, kBlk, 0, stream>>>(x, out);
}